// Round 11
// baseline (40486.655 us; speedup 1.0000x reference)
//
#include <hip/hip_runtime.h>
#include <math.h>

// R11: THE FIX — d_out is FLOAT32 (reference output dtype), not bf16.
// Evidence: R8/R9 probes (out[0]=64+ as u16) reported the all-zeros signature ->
// u16 landed as f32-denormal low half; bit-constant 8.119106e-03 across all variants
// = kappa*sigma of ref_0's back half vs our packed-u16 garbage; R0's 3.433e-3 matches
// healthy h-flavored ref max. Math (R6 golden, verified 5 independent ways) unchanged;
// only the store dtype changes.

__device__ __forceinline__ float sigm(float x){ return 1.0f/(1.0f + expf(-x)); }

struct GoldP {
  const int* ids;     // [N, T] int32
  const float* emb;   // [32000, 256] f32
  const float* Wih;   // [2048, 256] f32
  const float* Whh;   // [2048, 512] f32
  const float* bias;  // [2048] f32
  float* hN;          // [N, 512] f32 out (final h)
  float* cN;          // [N, 512] f32 out (final c)
  int T;
  int nblk;           // N / 8
};

// One block = 8 sequences start-to-finish; h/c live in LDS. (Verbatim from R6.)
__global__ __launch_bounds__(256) void golden_lstm_kernel(GoldP sc, GoldP cm, GoldP is)
{
  GoldP P; int blk;
  {
    int idx = blockIdx.x;
    if (idx < sc.nblk){ P = sc; blk = idx; }
    else if (idx < sc.nblk + cm.nblk){ P = cm; blk = idx - sc.nblk; }
    else { P = is; blk = idx - sc.nblk - cm.nblk; }
  }
  __shared__ float xs[8][256];
  __shared__ float hs[8][512];
  __shared__ float cs[8][512];
  const int s0 = blk*8, tid = threadIdx.x;

  for (int e = tid; e < 8*512; e += 256){ hs[e>>9][e&511] = 0.f; cs[e>>9][e&511] = 0.f; }
  __syncthreads();

  for (int t = 0; t < P.T; ++t){
    for (int e = tid; e < 8*256; e += 256){
      int s = e >> 8, k = e & 255;
      int id = P.ids[(size_t)(s0+s)*P.T + t];
      xs[s][k] = P.emb[(size_t)id*256 + k];
    }
    __syncthreads();

    float zv[8][8];   // [uu][seq]; unit u = tid + 256*uu; gate g = u>>9; j = u&511
    #pragma unroll
    for (int uu = 0; uu < 8; ++uu){
      const int u = tid + 256*uu;
      const float* wih = P.Wih + (size_t)u*256;
      const float* whh = P.Whh + (size_t)u*512;
      float z[8];
      float z0 = P.bias[u];
      #pragma unroll
      for (int s=0;s<8;++s) z[s] = z0;
      for (int k=0;k<256;++k){
        float w = wih[k];
        #pragma unroll
        for (int s=0;s<8;++s) z[s] += w * xs[s][k];
      }
      for (int k=0;k<512;++k){
        float w = whh[k];
        #pragma unroll
        for (int s=0;s<8;++s) z[s] += w * hs[s][k];
      }
      #pragma unroll
      for (int s=0;s<8;++s) zv[uu][s] = z[s];
    }
    __syncthreads();

    #pragma unroll
    for (int jj=0; jj<2; ++jj){
      const int j = tid + 256*jj;    // uu = 2g + jj for gate g (order i,f,g,o)
      #pragma unroll
      for (int s=0;s<8;++s){
        float zi = zv[0+jj][s];
        float zf = zv[2+jj][s];
        float zg = zv[4+jj][s];
        float zo = zv[6+jj][s];
        float cn = sigm(zf)*cs[s][j] + sigm(zi)*tanhf(zg);
        float hn = sigm(zo)*tanhf(cn);
        cs[s][j] = cn;
        hs[s][j] = hn;
      }
    }
    __syncthreads();
  }

  for (int e = tid; e < 8*512; e += 256){
    int s = e >> 9, j = e & 511;
    P.hN[(size_t)(s0+s)*512 + j] = hs[s][j];
    P.cN[(size_t)(s0+s)*512 + j] = cs[s][j];
  }
}

// kind=0: h = [hm | h_is] @ Wfh.T + bfh -> out[0:32768]
// kind=1: c = [cmm | c_is] @ Wfc.T + bfc -> out[32768:65536]
// Native f32 stores. Grid 128 = 64 b x 2 kind; full out coverage.
__global__ __launch_bounds__(256) void golden_out_kernel(
    const float* hsc, const float* hcm, const float* his,
    const float* csc, const float* ccm, const float* cis,
    const float* Wmh, const float* bmh, const float* Wmc, const float* bmc,
    const float* Wfh, const float* bfh, const float* Wfc, const float* bfc,
    float* out)
{
  const int b = blockIdx.x >> 1, kind = blockIdx.x & 1, tid = threadIdx.x;
  const float* S1 = kind ? csc : hsc;
  const float* S2 = kind ? ccm : hcm;
  const float* SI = kind ? cis : his;
  const float* Wm = kind ? Wmc : Wmh;
  const float* bm = kind ? bmc : bmh;
  const float* Wf = kind ? Wfc : Wfh;
  const float* bf = kind ? bfc : bfh;

  __shared__ float red[256];
  __shared__ float hmb[10];
  for (int nc = 0; nc < 10; ++nc){
    size_t n = (size_t)b*10 + nc;
    float a = 0.f;
    for (int k = tid; k < 512; k += 256)
      a += Wm[k]*S1[n*512+k] + Wm[512+k]*S2[n*512+k];
    red[tid] = a; __syncthreads();
    for (int s = 128; s > 0; s >>= 1){
      if (tid < s) red[tid] += red[tid+s];
      __syncthreads();
    }
    if (tid == 0) hmb[nc] = red[0] + bm[0];
    __syncthreads();
  }

  for (int uu = 0; uu < 2; ++uu){
    int u = tid + 256*uu;
    const float* wr = Wf + (size_t)u*522;
    float acc = bf[u];
    #pragma unroll
    for (int k=0;k<10;++k) acc += wr[k]*hmb[k];
    for (int k=0;k<512;++k) acc += wr[10+k]*SI[(size_t)b*512+k];
    out[(size_t)kind*32768 + (size_t)b*512 + u] = acc;   // FLOAT32 store
  }
}

extern "C" void kernel_launch(void* const* d_in, const int* in_sizes, int n_in,
                              void* d_out, int out_size, void* d_ws, size_t ws_size,
                              hipStream_t stream) {
  const int* comments = (const int*)d_in[0];
  const int* cm_ids   = (const int*)d_in[1];
  const int* issue    = (const int*)d_in[2];
  const float* emb_sc = (const float*)d_in[3];
  const float* emb_cm = (const float*)d_in[4];
  const float* emb_is = (const float*)d_in[5];
  const float* Wih_sc = (const float*)d_in[6];
  const float* Whh_sc = (const float*)d_in[7];
  const float* b_sc   = (const float*)d_in[8];
  const float* Wih_cm = (const float*)d_in[9];
  const float* Whh_cm = (const float*)d_in[10];
  const float* b_cm   = (const float*)d_in[11];
  const float* Wih_is = (const float*)d_in[12];
  const float* Whh_is = (const float*)d_in[13];
  const float* b_is   = (const float*)d_in[14];
  const float* Wmh = (const float*)d_in[15];
  const float* bmh = (const float*)d_in[16];
  const float* Wmc = (const float*)d_in[17];
  const float* bmc = (const float*)d_in[18];
  const float* Wfh = (const float*)d_in[19];
  const float* bfh = (const float*)d_in[20];
  const float* Wfc = (const float*)d_in[21];
  const float* bfc = (const float*)d_in[22];

  char* p = (char*)d_ws;
  float* h_sc = (float*)p; p += (size_t)640*512*4;
  float* c_sc = (float*)p; p += (size_t)640*512*4;
  float* h_cm = (float*)p; p += (size_t)640*512*4;
  float* c_cm = (float*)p; p += (size_t)640*512*4;
  float* h_is = (float*)p; p += (size_t)64*512*4;
  float* c_is = (float*)p; p += (size_t)64*512*4;

  GoldP Psc = { comments, emb_sc, Wih_sc, Whh_sc, b_sc, h_sc, c_sc, 128, 80 };
  GoldP Pcm = { cm_ids,   emb_cm, Wih_cm, Whh_cm, b_cm, h_cm, c_cm,  64, 80 };
  GoldP Pis = { issue,    emb_is, Wih_is, Whh_is, b_is, h_is, c_is,  32,  8 };

  golden_lstm_kernel<<<168, 256, 0, stream>>>(Psc, Pcm, Pis);
  golden_out_kernel<<<128, 256, 0, stream>>>(h_sc, h_cm, h_is, c_sc, c_cm, c_is,
                                             Wmh, bmh, Wmc, bmc, Wfh, bfh, Wfc, bfc,
                                             (float*)d_out);
}

// Round 12
// 5057.760 us; speedup vs baseline: 8.0049x; 8.0049x over previous
//
#include <hip/hip_runtime.h>
#include <math.h>

#define E 256
#define Hh 512

typedef __attribute__((ext_vector_type(8))) short short8;
typedef __attribute__((ext_vector_type(4))) float f32x4;

// R12: MFMA per-step kernels on the R11-verified data flow. Output f32 (the R11 fix).
// bf16 weight caches in ws at R3's exact proven 14.95 MB extent; h state bf16
// (double-buffered), c state f32. 32-wide j-tiles -> 336/320/160-block step grids.

struct LstmP {
  const int* ids;
  const float* emb;            // f32 embedding table (cvt to bf16 in-kernel)
  const unsigned short* Wih;   // bf16 ws cache [2048,256]
  const unsigned short* Whh;   // bf16 ws cache [2048,512]
  const float* bias;           // f32 [2048]
  const unsigned short* h_in;  // [N,512] bf16 ws
  unsigned short* h_out;       // [N,512] bf16 ws
  float* c;                    // [N,512] f32 ws
  int T;
};

__device__ __forceinline__ float bf2f(unsigned short x){
  union { unsigned u; float f; } v; v.u = ((unsigned)x) << 16; return v.f;
}
__device__ __forceinline__ unsigned short f2bf(float f){
  union { float f; unsigned u; } v; v.f = f;
  unsigned u = v.u;
  return (unsigned short)((u + 0x7fffu + ((u >> 16) & 1u)) >> 16);
}
__device__ __forceinline__ short8 cvt8(const float* p){
  f32x4 x = *(const f32x4*)p;
  f32x4 y = *(const f32x4*)(p + 4);
  short8 r;
  r[0]=(short)f2bf(x[0]); r[1]=(short)f2bf(x[1]); r[2]=(short)f2bf(x[2]); r[3]=(short)f2bf(x[3]);
  r[4]=(short)f2bf(y[0]); r[5]=(short)f2bf(y[1]); r[6]=(short)f2bf(y[2]); r[7]=(short)f2bf(y[3]);
  return r;
}
__device__ __forceinline__ float sigm(float x){ return 1.0f/(1.0f + expf(-x)); }

__global__ void zero_ws_kernel(uint4* p, int n){
  int i = blockIdx.x*256 + threadIdx.x;
  if (i < n){ uint4 z; z.x=0u; z.y=0u; z.z=0u; z.w=0u; p[i]=z; }
}

// f32 -> bf16 (RNE), 8 elems/thread. (R3-proven: produced cache bit-matching direct reads.)
__global__ __launch_bounds__(256) void cvt_kernel(const float* src, unsigned short* dst, int n8){
  int i = blockIdx.x*256 + threadIdx.x;
  if (i < n8){
    *(short8*)(dst + (size_t)i*8) = cvt8(src + (size_t)i*8);
  }
}

// One time-step for up to 3 LSTMs. Block tile: 64 batch x 32 hidden units.
// 4 waves; wave w computes gate w (rows w*512 + j0 + ...). K = 256 (emb) + 512 (h).
__global__ __launch_bounds__(256) void lstm_step_kernel(LstmP sc, LstmP cm, LstmP is,
                                                        int n_sc, int n_cm, int t)
{
  __shared__ float zb[4][64][32];   // 32 KB; col-swizzle keeps LDS <=2-way (free)
  LstmP P; int tile;
  {
    int idx = blockIdx.x;
    if (idx < n_sc){ P = sc; tile = idx; }
    else if (idx < n_sc + n_cm){ P = cm; tile = idx - n_sc; }
    else { P = is; tile = idx - n_sc - n_cm; }
  }
  const int tid  = threadIdx.x;
  const int w    = tid >> 6;       // gate 0..3 = i,f,g,o
  const int lane = tid & 63;
  const int l15  = lane & 15;
  const int q    = lane >> 4;
  const int mb = tile >> 4, jt = tile & 15;
  const int m0 = mb*64, j0 = jt*32;

  const float* ap1[4];            // f32 emb rows (A row = l15)
  const unsigned short* ap2[4];   // bf16 h rows
  #pragma unroll
  for (int mi=0; mi<4; ++mi){
    int m = m0 + mi*16 + l15;
    int id = P.ids[m*P.T + t];
    ap1[mi] = P.emb  + (size_t)id*E + q*8;
    ap2[mi] = P.h_in + (size_t)m*Hh + q*8;
  }
  const unsigned short* bp1[2];   // bf16 Wih rows (B row = gate unit = l15)
  const unsigned short* bp2[2];
  #pragma unroll
  for (int ni=0; ni<2; ++ni){
    int n = w*Hh + j0 + ni*16 + l15;
    bp1[ni] = P.Wih + (size_t)n*E  + q*8;
    bp2[ni] = P.Whh + (size_t)n*Hh + q*8;
  }

  f32x4 acc[4][2];
  #pragma unroll
  for (int i=0;i<4;++i)
    #pragma unroll
    for (int j=0;j<2;++j) acc[i][j] = (f32x4){0.f,0.f,0.f,0.f};

  // Phase 1: K=0..255, x = emb (cvt f32->bf16), W = Wih (bf16 cache)
  for (int kc=0; kc<8; ++kc){
    short8 a[4], b[2];
    #pragma unroll
    for (int mi=0;mi<4;++mi) a[mi] = cvt8(ap1[mi] + kc*32);
    #pragma unroll
    for (int ni=0;ni<2;++ni) b[ni] = *(const short8*)(bp1[ni] + kc*32);
    #pragma unroll
    for (int mi=0;mi<4;++mi)
      #pragma unroll
      for (int ni=0;ni<2;++ni)
        acc[mi][ni] = __builtin_amdgcn_mfma_f32_16x16x32_bf16(a[mi], b[ni], acc[mi][ni], 0,0,0);
  }
  // Phase 2: K=256..767, x = h (bf16), W = Whh (bf16 cache)
  for (int kc=0; kc<16; ++kc){
    short8 a[4], b[2];
    #pragma unroll
    for (int mi=0;mi<4;++mi) a[mi] = *(const short8*)(ap2[mi] + kc*32);
    #pragma unroll
    for (int ni=0;ni<2;++ni) b[ni] = *(const short8*)(bp2[ni] + kc*32);
    #pragma unroll
    for (int mi=0;mi<4;++mi)
      #pragma unroll
      for (int ni=0;ni<2;++ni)
        acc[mi][ni] = __builtin_amdgcn_mfma_f32_16x16x32_bf16(a[mi], b[ni], acc[mi][ni], 0,0,0);
  }

  float bv[2];
  #pragma unroll
  for (int ni=0;ni<2;++ni) bv[ni] = P.bias[w*Hh + j0 + ni*16 + l15];

  // C/D layout (m89-verified; R4==R5 bit-identity re-verified): row = q*4+r, col = l15
  #pragma unroll
  for (int mi=0;mi<4;++mi)
    #pragma unroll
    for (int ni=0;ni<2;++ni)
      #pragma unroll
      for (int r=0;r<4;++r){
        int m = mi*16 + q*4 + r;
        int col = (ni*16 + l15 + q*8) & 31;     // swizzled store (2-way max)
        zb[w][m][col] = acc[mi][ni][r] + bv[ni];
      }
  __syncthreads();

  for (int e = tid; e < 64*32; e += 256){
    int m = e >> 5, j = e & 31;
    int cs = (j + ((m>>2)&3)*8) & 31;           // matching swizzled load
    float zi = zb[0][m][cs], zf = zb[1][m][cs], zg = zb[2][m][cs], zo = zb[3][m][cs];
    int gi = (m0 + m)*Hh + j0 + j;
    float cold = P.c[gi];
    float cn = sigm(zf)*cold + sigm(zi)*tanhf(zg);
    float hn = sigm(zo)*tanhf(cn);
    P.c[gi] = cn;
    P.h_out[gi] = f2bf(hn);
  }
}

// Output kernel (R11-proven structure; h inputs now bf16, c inputs f32, out f32).
// kind=0: [hm | h_is] @ Wfh.T + bfh -> out[0:32768]; kind=1: c-flavored -> out[32768:].
__global__ __launch_bounds__(256) void out_kernel(
    const unsigned short* hsc, const unsigned short* hcm, const unsigned short* his,
    const float* csc, const float* ccm, const float* cis,
    const float* Wmh, const float* bmh, const float* Wmc, const float* bmc,
    const float* Wfh, const float* bfh, const float* Wfc, const float* bfc,
    float* out)
{
  const int b = blockIdx.x >> 1, kind = blockIdx.x & 1, tid = threadIdx.x;
  const float* Wm = kind ? Wmc : Wmh;
  const float* bm = kind ? bmc : bmh;
  const float* Wf = kind ? Wfc : Wfh;
  const float* bf = kind ? bfc : bfh;

  __shared__ float red[256];
  __shared__ float hmb[10];
  for (int nc = 0; nc < 10; ++nc){
    size_t n = (size_t)b*10 + nc;
    float a = 0.f;
    for (int k = tid; k < 512; k += 256){
      float v1 = kind ? csc[n*512+k] : bf2f(hsc[n*512+k]);
      float v2 = kind ? ccm[n*512+k] : bf2f(hcm[n*512+k]);
      a += Wm[k]*v1 + Wm[512+k]*v2;
    }
    red[tid] = a; __syncthreads();
    for (int s = 128; s > 0; s >>= 1){
      if (tid < s) red[tid] += red[tid+s];
      __syncthreads();
    }
    if (tid == 0) hmb[nc] = red[0] + bm[0];
    __syncthreads();
  }

  for (int uu = 0; uu < 2; ++uu){
    int u = tid + 256*uu;
    const float* wr = Wf + (size_t)u*522;
    float acc = bf[u];
    #pragma unroll
    for (int k=0;k<10;++k) acc += wr[k]*hmb[k];
    for (int k=0;k<512;++k){
      float v = kind ? cis[(size_t)b*512+k] : bf2f(his[(size_t)b*512+k]);
      acc += wr[10+k]*v;
    }
    out[(size_t)kind*32768 + (size_t)b*512 + u] = acc;   // f32 store
  }
}

extern "C" void kernel_launch(void* const* d_in, const int* in_sizes, int n_in,
                              void* d_out, int out_size, void* d_ws, size_t ws_size,
                              hipStream_t stream) {
  const int* comments = (const int*)d_in[0];
  const int* cm_ids   = (const int*)d_in[1];
  const int* issue    = (const int*)d_in[2];
  const float* emb_sc = (const float*)d_in[3];
  const float* emb_cm = (const float*)d_in[4];
  const float* emb_is = (const float*)d_in[5];
  const float* Wih_sc = (const float*)d_in[6];
  const float* Whh_sc = (const float*)d_in[7];
  const float* b_sc   = (const float*)d_in[8];
  const float* Wih_cm = (const float*)d_in[9];
  const float* Whh_cm = (const float*)d_in[10];
  const float* b_cm   = (const float*)d_in[11];
  const float* Wih_is = (const float*)d_in[12];
  const float* Whh_is = (const float*)d_in[13];
  const float* b_is   = (const float*)d_in[14];
  const float* Wmh = (const float*)d_in[15];
  const float* bmh = (const float*)d_in[16];
  const float* Wmc = (const float*)d_in[17];
  const float* bmc = (const float*)d_in[18];
  const float* Wfh = (const float*)d_in[19];
  const float* bfh = (const float*)d_in[20];
  const float* Wfc = (const float*)d_in[21];
  const float* bfc = (const float*)d_in[22];

  // Workspace (14.94 MB total == R3's proven extent)
  char* p = (char*)d_ws;
  unsigned short* hb_sc = (unsigned short*)p; p += (size_t)2*640*512*2;
  unsigned short* hb_cm = (unsigned short*)p; p += (size_t)2*640*512*2;
  unsigned short* hb_is = (unsigned short*)p; p += (size_t)2*64*512*2;
  float* c_sc = (float*)p; p += (size_t)640*512*4;
  float* c_cm = (float*)p; p += (size_t)640*512*4;
  float* c_is = (float*)p; p += (size_t)64*512*4;
  size_t zero_bytes = (size_t)(p - (char*)d_ws);
  unsigned short* Wih_sc_b = (unsigned short*)p; p += (size_t)2048*256*2;
  unsigned short* Whh_sc_b = (unsigned short*)p; p += (size_t)2048*512*2;
  unsigned short* Wih_cm_b = (unsigned short*)p; p += (size_t)2048*256*2;
  unsigned short* Whh_cm_b = (unsigned short*)p; p += (size_t)2048*512*2;
  unsigned short* Wih_is_b = (unsigned short*)p; p += (size_t)2048*256*2;
  unsigned short* Whh_is_b = (unsigned short*)p; p += (size_t)2048*512*2;

  int n4 = (int)(zero_bytes/16);
  zero_ws_kernel<<<(n4+255)/256, 256, 0, stream>>>((uint4*)d_ws, n4);

  const int nih8 = 2048*256/8, nhh8 = 2048*512/8;
  cvt_kernel<<<(nih8+255)/256, 256, 0, stream>>>(Wih_sc, Wih_sc_b, nih8);
  cvt_kernel<<<(nhh8+255)/256, 256, 0, stream>>>(Whh_sc, Whh_sc_b, nhh8);
  cvt_kernel<<<(nih8+255)/256, 256, 0, stream>>>(Wih_cm, Wih_cm_b, nih8);
  cvt_kernel<<<(nhh8+255)/256, 256, 0, stream>>>(Whh_cm, Whh_cm_b, nhh8);
  cvt_kernel<<<(nih8+255)/256, 256, 0, stream>>>(Wih_is, Wih_is_b, nih8);
  cvt_kernel<<<(nhh8+255)/256, 256, 0, stream>>>(Whh_is, Whh_is_b, nhh8);

  for (int t = 0; t < 128; ++t){
    LstmP Psc = { comments, emb_sc, Wih_sc_b, Whh_sc_b, b_sc,
                  hb_sc + (size_t)(t&1)*640*512, hb_sc + (size_t)((t+1)&1)*640*512,
                  c_sc, 128 };
    LstmP Pcm = { cm_ids, emb_cm, Wih_cm_b, Whh_cm_b, b_cm,
                  hb_cm + (size_t)(t&1)*640*512, hb_cm + (size_t)((t+1)&1)*640*512,
                  c_cm, 64 };
    LstmP Pis = { issue, emb_is, Wih_is_b, Whh_is_b, b_is,
                  hb_is + (size_t)(t&1)*64*512, hb_is + (size_t)((t+1)&1)*64*512,
                  c_is, 32 };
    int ncm = (t < 64) ? 160 : 0;
    int nis = (t < 32) ? 16 : 0;
    lstm_step_kernel<<<160 + ncm + nis, 256, 0, stream>>>(Psc, Pcm, Pis, 160, ncm, t);
  }

  // Final h states in buffer 0 for all three (sc t=127 -> (128&1)=0; cm t=63; is t=31).
  out_kernel<<<128, 256, 0, stream>>>(hb_sc, hb_cm, hb_is, c_sc, c_cm, c_is,
                                      Wmh, bmh, Wmc, bmc, Wfh, bfh, Wfc, bfc,
                                      (float*)d_out);
}